// Round 7
// baseline (1017.503 us; speedup 1.0000x reference)
//
#include <hip/hip_runtime.h>

// ---------------------------------------------------------------------------
// GATv2 x4 + MLP readout.  CSR-by-dst build once per call, then per layer:
//   k_transform: xl = x@Wl+bl, xr = x@Wr+br  (64 nodes/block, 4n x 4c/thread)
//   k_edge: fused score + online-softmax + aggregate. One wave per NODE,
//     chunk = 16 edges.  Staging: 4 rows per global_load_lds (size=16,
//     per-lane gather addresses), channel groups ROTATED by row so the
//     unpadded stride-64 tile reads conflict-free.  Score lane=(e,q) dots 16
//     channels of edge e; aggregate accumulates acc16 in REGISTERS (no LDS
//     reads, no readlanes); one butterfly over e per node at the end.
// CSR build: hist -> scanA -> scanC(+B fused) -> k_scatter (LDS-binned,
//   ~77k spread global atomics) -> k_csr (bucket-local scatter).
// Readout: per-block partial sums (no atomics) + 1-block MLP.
// NOTE: packing requires N <= 65536 (here N = 50000).
// R5 lesson: per-edge global atomics on few lines serialize (~11ns/op).
// ---------------------------------------------------------------------------

__device__ __forceinline__ int rfl(int v) { return __builtin_amdgcn_readfirstlane(v); }

__device__ __forceinline__ void row16_to_lds(const float* g, float* l) {
  __builtin_amdgcn_global_load_lds((const __attribute__((address_space(1))) void*)g,
                                   (__attribute__((address_space(3))) void*)l,
                                   16, 0, 0);
}

__global__ void k_hist(const int* __restrict__ dst, int* __restrict__ deg, int E) {
  int e = blockIdx.x * blockDim.x + threadIdx.x;
  if (e < E) atomicAdd(&deg[dst[e]], 1);
}

// ---- scan pass A: per-1024-chunk sums
__global__ void __launch_bounds__(256) k_scanA(const int* __restrict__ deg,
                                               int* __restrict__ bsum, int n) {
  __shared__ int ws[4];
  int tid = threadIdx.x, lane = tid & 63, wv = tid >> 6;
  int base = blockIdx.x * 1024 + tid;
  int s = 0;
  #pragma unroll
  for (int k = 0; k < 4; k++) {
    int i = base + k * 256;
    if (i < n) s += deg[i];
  }
  #pragma unroll
  for (int o = 32; o > 0; o >>= 1) s += __shfl_xor(s, o, 64);
  if (lane == 0) ws[wv] = s;
  __syncthreads();
  if (tid == 0) bsum[blockIdx.x] = ws[0] + ws[1] + ws[2] + ws[3];
}

// ---- scan pass C (with pass B folded in: every block re-scans bsum)
__global__ void __launch_bounds__(256) k_scanC(const int* __restrict__ deg,
                                               const int* __restrict__ bsum,
                                               int* __restrict__ rowptr, int n, int nb) {
  __shared__ int wtot[4];
  __shared__ int sboff;
  int tid = threadIdx.x, lane = tid & 63, wv = tid >> 6;
  if (wv == 0) {
    int v = (lane < nb) ? bsum[lane] : 0;  // nb <= 64
    int x = v;
    #pragma unroll
    for (int o = 1; o < 64; o <<= 1) {
      int t = __shfl_up(x, o, 64);
      if (lane >= o) x += t;
    }
    if (lane == (int)blockIdx.x) sboff = x - v;     // exclusive prefix for this block
    if (blockIdx.x == 0 && lane == 63) rowptr[n] = x;  // grand total
  }
  __syncthreads();
  int i0 = blockIdx.x * 1024 + tid * 4;
  int4 v = make_int4(0, 0, 0, 0);
  if (i0 + 3 < n) v = *(const int4*)(deg + i0);
  else {
    if (i0 + 0 < n) v.x = deg[i0 + 0];
    if (i0 + 1 < n) v.y = deg[i0 + 1];
    if (i0 + 2 < n) v.z = deg[i0 + 2];
  }
  int s = v.x + v.y + v.z + v.w;
  int x = s;
  #pragma unroll
  for (int o = 1; o < 64; o <<= 1) {
    int t = __shfl_up(x, o, 64);
    if (lane >= o) x += t;
  }
  if (lane == 63) wtot[wv] = x;
  __syncthreads();
  int wexcl = 0;
  for (int k = 0; k < 4; k++) if (k < wv) wexcl += wtot[k];
  int excl = sboff + wexcl + (x - s);
  int4 o4;
  o4.x = excl; o4.y = o4.x + v.x; o4.z = o4.y + v.y; o4.w = o4.z + v.z;
  if (i0 + 3 < n) *(int4*)(rowptr + i0) = o4;
  else {
    if (i0 + 0 < n) rowptr[i0 + 0] = o4.x;
    if (i0 + 1 < n) rowptr[i0 + 1] = o4.y;
    if (i0 + 2 < n) rowptr[i0 + 2] = o4.z;
  }
}

// ---- pass 1: block-binned scatter into bucket regions (256 dst per bucket)
#define NBK_MAX 256
__global__ void __launch_bounds__(256) k_scatter(
    const int* __restrict__ src, const int* __restrict__ dst,
    const float* __restrict__ ea_in, const int* __restrict__ rowptr,
    int* __restrict__ bcur, uint2* __restrict__ tmp, int E, int nbk) {
  __shared__ int cnt[NBK_MAX];
  __shared__ int cur[NBK_MAX];
  __shared__ int gbase[NBK_MAX];
  __shared__ int sbase[NBK_MAX];
  int tid = threadIdx.x;
  if (tid < nbk) {
    cnt[tid] = 0;
    cur[tid] = 0;
    sbase[tid] = rowptr[tid << 8];
  }
  __syncthreads();
  int base = blockIdx.x * 4096 + tid;
  uint2 rec[16];
  #pragma unroll
  for (int k = 0; k < 16; k++) {
    int e = base + k * 256;
    if (e < E) {
      unsigned d = (unsigned)dst[e];
      rec[k] = make_uint2((d << 16) | (unsigned)src[e],
                          (unsigned)__float_as_int(ea_in[e]));
      atomicAdd(&cnt[d >> 8], 1);
    } else {
      rec[k] = make_uint2(0u, 0u);
    }
  }
  __syncthreads();
  if (tid < nbk) {
    int c = cnt[tid];
    gbase[tid] = (c > 0) ? atomicAdd(&bcur[tid * 16], c) : 0;
  }
  __syncthreads();
  #pragma unroll
  for (int k = 0; k < 16; k++) {
    int e = base + k * 256;
    if (e < E) {
      int b = (int)(rec[k].x >> 24);
      int slot = atomicAdd(&cur[b], 1);
      tmp[sbase[b] + gbase[b] + slot] = rec[k];
    }
  }
}

// ---- pass 2: one block per bucket; LDS cursors; L2-resident final scatter
__global__ void __launch_bounds__(256) k_csr(const int* __restrict__ rowptr,
                                             const uint2* __restrict__ tmp,
                                             int2* __restrict__ pairs, int N) {
  __shared__ int sRP[257];
  __shared__ int cur[256];
  int b = blockIdx.x;
  int n0 = b << 8;
  int tid = threadIdx.x;
  sRP[tid] = rowptr[min(n0 + tid, N)];
  if (tid == 0) sRP[256] = rowptr[min(n0 + 256, N)];
  cur[tid] = 0;
  __syncthreads();
  int lo = sRP[0], hi = sRP[256];
  for (int k = lo + tid; k < hi; k += 256) {
    uint2 rec = tmp[k];
    int local = (int)(rec.x >> 16) - n0;
    int pos = sRP[local] + atomicAdd(&cur[local], 1);
    pairs[pos] = make_int2((int)(rec.x & 0xffffu), (int)rec.y);
  }
}

// xl = x@Wl+bl ; xr = x@Wr+br.  64 nodes/block; thread = 4 nodes x 4 cols.
// Weight LDS b128 reads amortized over 4 nodes; x staged transposed.
template <int DIN>
__global__ void __launch_bounds__(256) k_transform(
    const float* __restrict__ x, const float* __restrict__ Wl, const float* __restrict__ bl,
    const float* __restrict__ Wr, const float* __restrict__ br,
    float* __restrict__ xl, float* __restrict__ xr, int nNodes) {
  __shared__ __align__(16) float sWl[DIN * 64];
  __shared__ __align__(16) float sWr[DIN * 64];
  __shared__ __align__(16) float sxT[DIN][65];  // [channel][node], +1 pad
  int tid = threadIdx.x;
  for (int i = tid; i < DIN * 64; i += 256) { sWl[i] = Wl[i]; sWr[i] = Wr[i]; }
  int nb = blockIdx.x * 64;
  for (int i = tid; i < 64 * DIN; i += 256) {
    int node = i / DIN, c = i % DIN;     // coalesced global read
    int g = nb + node;
    sxT[c][node] = (g < nNodes) ? x[(size_t)g * DIN + c] : 0.f;
  }
  __syncthreads();
  int c4 = (tid & 15) * 4;      // column group
  int ns = (tid >> 4) * 4;      // first of 4 nodes
  float4 bl4 = *(const float4*)(bl + c4);
  float4 br4 = *(const float4*)(br + c4);
  float4 accl0 = bl4, accl1 = bl4, accl2 = bl4, accl3 = bl4;
  float4 accr0 = br4, accr1 = br4, accr2 = br4, accr3 = br4;
  #pragma unroll 4
  for (int k = 0; k < DIN; k++) {
    float4 wl = *(const float4*)(sWl + k * 64 + c4);
    float4 wr = *(const float4*)(sWr + k * 64 + c4);
    float4 xv = *(const float4*)(&sxT[k][ns]);
    accl0.x = fmaf(xv.x, wl.x, accl0.x); accl0.y = fmaf(xv.x, wl.y, accl0.y);
    accl0.z = fmaf(xv.x, wl.z, accl0.z); accl0.w = fmaf(xv.x, wl.w, accl0.w);
    accr0.x = fmaf(xv.x, wr.x, accr0.x); accr0.y = fmaf(xv.x, wr.y, accr0.y);
    accr0.z = fmaf(xv.x, wr.z, accr0.z); accr0.w = fmaf(xv.x, wr.w, accr0.w);
    accl1.x = fmaf(xv.y, wl.x, accl1.x); accl1.y = fmaf(xv.y, wl.y, accl1.y);
    accl1.z = fmaf(xv.y, wl.z, accl1.z); accl1.w = fmaf(xv.y, wl.w, accl1.w);
    accr1.x = fmaf(xv.y, wr.x, accr1.x); accr1.y = fmaf(xv.y, wr.y, accr1.y);
    accr1.z = fmaf(xv.y, wr.z, accr1.z); accr1.w = fmaf(xv.y, wr.w, accr1.w);
    accl2.x = fmaf(xv.z, wl.x, accl2.x); accl2.y = fmaf(xv.z, wl.y, accl2.y);
    accl2.z = fmaf(xv.z, wl.z, accl2.z); accl2.w = fmaf(xv.z, wl.w, accl2.w);
    accr2.x = fmaf(xv.z, wr.x, accr2.x); accr2.y = fmaf(xv.z, wr.y, accr2.y);
    accr2.z = fmaf(xv.z, wr.z, accr2.z); accr2.w = fmaf(xv.z, wr.w, accr2.w);
    accl3.x = fmaf(xv.w, wl.x, accl3.x); accl3.y = fmaf(xv.w, wl.y, accl3.y);
    accl3.z = fmaf(xv.w, wl.z, accl3.z); accl3.w = fmaf(xv.w, wl.w, accl3.w);
    accr3.x = fmaf(xv.w, wr.x, accr3.x); accr3.y = fmaf(xv.w, wr.y, accr3.y);
    accr3.z = fmaf(xv.w, wr.z, accr3.z); accr3.w = fmaf(xv.w, wr.w, accr3.w);
  }
  int g0 = nb + ns;
  if (g0 + 0 < nNodes) { *(float4*)(xl + (size_t)(g0+0)*64 + c4) = accl0; *(float4*)(xr + (size_t)(g0+0)*64 + c4) = accr0; }
  if (g0 + 1 < nNodes) { *(float4*)(xl + (size_t)(g0+1)*64 + c4) = accl1; *(float4*)(xr + (size_t)(g0+1)*64 + c4) = accr1; }
  if (g0 + 2 < nNodes) { *(float4*)(xl + (size_t)(g0+2)*64 + c4) = accl2; *(float4*)(xr + (size_t)(g0+2)*64 + c4) = accr2; }
  if (g0 + 3 < nNodes) { *(float4*)(xl + (size_t)(g0+3)*64 + c4) = accl3; *(float4*)(xr + (size_t)(g0+3)*64 + c4) = accr3; }
}

// Fused score + online softmax + aggregate. One wave per node, chunk = 16.
#define SCGRP(T, W, X, A) \
  u = T.x + fmaf(ea, W.x, X.x); u = fmaxf(u, 0.2f * u); sc = fmaf(A.x, u, sc); \
  u = T.y + fmaf(ea, W.y, X.y); u = fmaxf(u, 0.2f * u); sc = fmaf(A.y, u, sc); \
  u = T.z + fmaf(ea, W.z, X.z); u = fmaxf(u, 0.2f * u); sc = fmaf(A.z, u, sc); \
  u = T.w + fmaf(ea, W.w, X.w); u = fmaxf(u, 0.2f * u); sc = fmaf(A.w, u, sc);
#define AGG(A, T) \
  A.x = fmaf(alpha, T.x, A.x * r); A.y = fmaf(alpha, T.y, A.y * r); \
  A.z = fmaf(alpha, T.z, A.z * r); A.w = fmaf(alpha, T.w, A.w * r);
#define BFLY(A, O) \
  A.x += __shfl_xor(A.x, O, 64); A.y += __shfl_xor(A.y, O, 64); \
  A.z += __shfl_xor(A.z, O, 64); A.w += __shfl_xor(A.w, O, 64);

__global__ void __launch_bounds__(256, 8) k_edge(
    const float* __restrict__ xl, const float* __restrict__ xr,
    const int* __restrict__ rowptr, const int* __restrict__ pairs,  // int2 as int*
    const float* __restrict__ We, const float* __restrict__ att,
    const float* __restrict__ bo, float* __restrict__ xout, int nNodes) {
  __shared__ __align__(16) float tile[4][16 * 64];  // 4 KB/wave, NO pad (DMA layout)
  __shared__ __align__(16) float sXr[4][64];
  __shared__ __align__(16) float sWe[64];
  __shared__ __align__(16) float sAtt[64];
  __shared__ __align__(16) float sBo[64];
  int tid = threadIdx.x;
  int lane = tid & 63;
  int wv = rfl(tid >> 6);
  int n = rfl(blockIdx.x * 4 + wv);
  if (tid < 64) { sWe[tid] = We[tid]; sAtt[tid] = att[tid]; sBo[tid] = bo[tid]; }
  bool active = (n < nNodes);
  if (active) sXr[wv][lane] = xr[(size_t)n * 64 + lane];
  __syncthreads();
  if (!active) return;

  float* tw = tile[wv];
  int s0 = rfl(rowptr[n]);
  int s1 = rfl(rowptr[n + 1]);
  int e = lane & 15, q = lane >> 4;

  // Kernel-invariant per-lane LDS read addresses.  Row r holds its channel
  // group gc at slot (gc - r) & 15  (rotation applied at fetch).
  const float* tr0 = tw + e * 64 + ((q * 4 + 0 - e) & 15) * 4;
  const float* tr1 = tw + e * 64 + ((q * 4 + 1 - e) & 15) * 4;
  const float* tr2 = tw + e * 64 + ((q * 4 + 2 - e) & 15) * 4;
  const float* tr3 = tw + e * 64 + ((q * 4 + 3 - e) & 15) * 4;
  const float* xq = sXr[wv] + q * 16;
  const float* wq = sWe + q * 16;
  const float* aq = sAtt + q * 16;
  int rsub = lane >> 4;   // row-in-quad for staging
  int slot = lane & 15;   // 16B slot within row

  float m = -3.0e38f, d = 0.f;
  float4 A0 = {0.f,0.f,0.f,0.f}, A1 = A0, A2 = A0, A3 = A0;

  for (int kb = s0; kb < s1; kb += 16) {
    int cnt = rfl(min(16, s1 - kb));
    int raw = 0;
    if (lane < 2 * cnt) raw = pairs[2 * kb + lane];
    float ea = __int_as_float(__shfl(raw, 2 * e + 1, 64));

    // stage 16 rows via 4 wide DMAs (each: 64 lanes x 16B = 4 rows, gather).
    // Padded rows read node 0 (valid memory, L1-hot); alpha=0 masks them.
    #pragma unroll
    for (int i = 0; i < 4; ++i) {
      int r = 4 * i + rsub;
      int s = __shfl(raw, 2 * r, 64);      // src of row r (0 for padded rows)
      int gc = (slot + r) & 15;            // rotated channel group
      row16_to_lds(xl + (size_t)(unsigned)s * 64 + gc * 4, tw + i * 256);
    }
    __builtin_amdgcn_s_waitcnt(0);

    // score: lane (e,q) dots channels [16q,16q+16) of edge e (conflict-free)
    float4 t0 = *(const float4*)tr0;
    float4 t1 = *(const float4*)tr1;
    float4 t2 = *(const float4*)tr2;
    float4 t3 = *(const float4*)tr3;
    float4 x0 = *(const float4*)(xq + 0),  x1 = *(const float4*)(xq + 4);
    float4 x2 = *(const float4*)(xq + 8),  x3 = *(const float4*)(xq + 12);
    float4 w0 = *(const float4*)(wq + 0),  w1 = *(const float4*)(wq + 4);
    float4 w2 = *(const float4*)(wq + 8),  w3 = *(const float4*)(wq + 12);
    float4 a0 = *(const float4*)(aq + 0),  a1 = *(const float4*)(aq + 4);
    float4 a2 = *(const float4*)(aq + 8),  a3 = *(const float4*)(aq + 12);
    float sc = 0.f, u;
    SCGRP(t0, w0, x0, a0)
    SCGRP(t1, w1, x1, a1)
    SCGRP(t2, w2, x2, a2)
    SCGRP(t3, w3, x3, a3)
    sc += __shfl_xor(sc, 16, 64);   // combine the 4 channel quarters
    sc += __shfl_xor(sc, 32, 64);
    sc = (e < cnt) ? sc : -3.0e38f; // padded edges -> alpha = 0

    // online softmax over 16 edges (quarter-duplicated lanes)
    float mc = sc;
    #pragma unroll
    for (int o = 1; o <= 8; o <<= 1) mc = fmaxf(mc, __shfl_xor(mc, o, 64));
    float newm = fmaxf(m, mc);
    float r = expf(m - newm);       // 0 on first chunk, 1 if max unchanged
    float alpha = expf(sc - newm);
    float ds = alpha;
    #pragma unroll
    for (int o = 1; o <= 8; o <<= 1) ds += __shfl_xor(ds, o, 64);
    d = d * r + ds;
    m = newm;

    // aggregate in registers: acc16 += alpha_e * tv  (no LDS reads)
    AGG(A0, t0) AGG(A1, t1) AGG(A2, t2) AGG(A3, t3)
  }

  // sum over the 16 edge-lanes within each q-group
  BFLY(A0, 1) BFLY(A1, 1) BFLY(A2, 1) BFLY(A3, 1)
  BFLY(A0, 2) BFLY(A1, 2) BFLY(A2, 2) BFLY(A3, 2)
  BFLY(A0, 4) BFLY(A1, 4) BFLY(A2, 4) BFLY(A3, 4)
  BFLY(A0, 8) BFLY(A1, 8) BFLY(A2, 8) BFLY(A3, 8)

  float inv = 1.f / (d + 1e-16f);
  if (e == 0) {
    float* op = xout + (size_t)n * 64 + q * 16;
    float4 b0 = *(const float4*)(sBo + q * 16 + 0);
    float4 b1 = *(const float4*)(sBo + q * 16 + 4);
    float4 b2 = *(const float4*)(sBo + q * 16 + 8);
    float4 b3 = *(const float4*)(sBo + q * 16 + 12);
    float4 o0, o1, o2, o3;
    o0.x = fmaxf(fmaf(A0.x, inv, b0.x), 0.f); o0.y = fmaxf(fmaf(A0.y, inv, b0.y), 0.f);
    o0.z = fmaxf(fmaf(A0.z, inv, b0.z), 0.f); o0.w = fmaxf(fmaf(A0.w, inv, b0.w), 0.f);
    o1.x = fmaxf(fmaf(A1.x, inv, b1.x), 0.f); o1.y = fmaxf(fmaf(A1.y, inv, b1.y), 0.f);
    o1.z = fmaxf(fmaf(A1.z, inv, b1.z), 0.f); o1.w = fmaxf(fmaf(A1.w, inv, b1.w), 0.f);
    o2.x = fmaxf(fmaf(A2.x, inv, b2.x), 0.f); o2.y = fmaxf(fmaf(A2.y, inv, b2.y), 0.f);
    o2.z = fmaxf(fmaf(A2.z, inv, b2.z), 0.f); o2.w = fmaxf(fmaf(A2.w, inv, b2.w), 0.f);
    o3.x = fmaxf(fmaf(A3.x, inv, b3.x), 0.f); o3.y = fmaxf(fmaf(A3.y, inv, b3.y), 0.f);
    o3.z = fmaxf(fmaf(A3.z, inv, b3.z), 0.f); o3.w = fmaxf(fmaf(A3.w, inv, b3.w), 0.f);
    *(float4*)(op + 0)  = o0;
    *(float4*)(op + 4)  = o1;
    *(float4*)(op + 8)  = o2;
    *(float4*)(op + 12) = o3;
  }
}

// per-block partial sums (no atomics); k_mlp reduces the 64 partials
__global__ void k_mean(const float* __restrict__ x, float* __restrict__ part, int nNodes) {
  __shared__ float sacc[256];
  int lane = threadIdx.x & 63;
  int gw = blockIdx.x * 4 + (threadIdx.x >> 6);
  int stride = gridDim.x * 4;
  float acc = 0.f;
  for (int n = gw; n < nNodes; n += stride) acc += x[(size_t)n * 64 + lane];
  sacc[threadIdx.x] = acc;
  __syncthreads();
  if (threadIdx.x < 64)
    part[blockIdx.x * 64 + threadIdx.x] =
        sacc[threadIdx.x] + sacc[threadIdx.x + 64] + sacc[threadIdx.x + 128] + sacc[threadIdx.x + 192];
}

__global__ void k_mlp(const float* __restrict__ part, int nparts,
                      const float* __restrict__ Wm1, const float* __restrict__ bm1,
                      const float* __restrict__ Wm2, const float* __restrict__ bm2,
                      const float* __restrict__ Wm3, const float* __restrict__ bm3,
                      float* __restrict__ out, double invN) {
  __shared__ float xm[64];
  __shared__ float h1[32];
  __shared__ float h2[16];
  int t = threadIdx.x;
  double s = 0.0;
  for (int b = 0; b < nparts; b++) s += (double)part[b * 64 + t];
  xm[t] = (float)(s * invN);
  __syncthreads();
  if (t < 32) {
    float a = bm1[t];
    for (int c = 0; c < 64; c++) a = fmaf(xm[c], Wm1[c * 32 + t], a);
    h1[t] = fmaxf(a, 0.f);
  }
  __syncthreads();
  if (t < 16) {
    float a = bm2[t];
    for (int c = 0; c < 32; c++) a = fmaf(h1[c], Wm2[c * 16 + t], a);
    h2[t] = fmaxf(a, 0.f);
  }
  __syncthreads();
  if (t == 0) {
    float a = bm3[0];
    for (int c = 0; c < 16; c++) a = fmaf(h2[c], Wm3[c], a);
    out[0] = a;
  }
}

extern "C" void kernel_launch(void* const* d_in, const int* in_sizes, int n_in,
                              void* d_out, int out_size, void* d_ws, size_t ws_size,
                              hipStream_t stream) {
  (void)n_in; (void)out_size; (void)ws_size;
  const int N = in_sizes[0] / 36;   // 50000
  const int E = in_sizes[1];        // 1600000

  const float* feat = (const float*)d_in[0];
  const float* eat  = (const float*)d_in[1];
  const int*   eidx = (const int*)d_in[2];
  const int* src = eidx;
  const int* dst = eidx + E;

  const float* L[4][7];  // Wl, bl, Wr, br, We, att, bo
  for (int l = 0; l < 4; l++)
    for (int j = 0; j < 7; j++) L[l][j] = (const float*)d_in[3 + l * 7 + j];
  const float* Wm1 = (const float*)d_in[31];
  const float* bm1 = (const float*)d_in[32];
  const float* Wm2 = (const float*)d_in[33];
  const float* bm2 = (const float*)d_in[34];
  const float* Wm3 = (const float*)d_in[35];
  const float* bm3 = (const float*)d_in[36];

  const int NBK = (N + 255) >> 8;  // buckets of 256 dst nodes (196)

  // workspace layout (512B aligned)
  char* ws = (char*)d_ws;
  size_t off = 0;
  auto alloc = [&](size_t bytes) {
    off = (off + 511) & ~(size_t)511;
    void* p = ws + off;
    off += bytes;
    return p;
  };
  int*    deg     = (int*)alloc((size_t)N * 4);
  int*    bcur    = (int*)alloc((size_t)NBK * 16 * 4);  // 1 counter per 64B line
  size_t zero_bytes = off;  // deg + bcur
  int*    rowptr  = (int*)alloc((size_t)(N + 1) * 4);
  int*    bsum    = (int*)alloc(64 * 4);
  float*  part    = (float*)alloc(64 * 64 * 4);
  int2*   pairs   = (int2*)alloc((size_t)E * 8);
  float*  xA      = (float*)alloc((size_t)N * 64 * 4);  // xl
  float*  xB      = (float*)alloc((size_t)N * 64 * 4);  // xr
  float*  xC      = (float*)alloc((size_t)N * 64 * 4);  // layer out / next in
  uint2*  tmp     = (uint2*)xC;  // aliases xC: dead until k_edge layer 1 writes it

  hipMemsetAsync(d_ws, 0, zero_bytes, stream);

  int egrid = (E + 255) / 256;
  int sgrid = (E + 4095) / 4096; // k_scatter: 4096 edges per 256-thr block
  int tgrid = (N + 63) / 64;     // k_transform: 64 nodes per 256-thr block
  int ngrid = (N + 3) / 4;       // k_edge: 4 nodes (waves) per 256-thr block
  int nb = (N + 1023) / 1024;    // scan blocks (49 <= 64)

  k_hist<<<egrid, 256, 0, stream>>>(dst, deg, E);
  k_scanA<<<nb, 256, 0, stream>>>(deg, bsum, N);
  k_scanC<<<nb, 256, 0, stream>>>(deg, bsum, rowptr, N, nb);
  k_scatter<<<sgrid, 256, 0, stream>>>(src, dst, eat, rowptr, bcur, tmp, E, NBK);
  k_csr<<<NBK, 256, 0, stream>>>(rowptr, tmp, pairs, N);

  for (int l = 0; l < 4; l++) {
    if (l == 0)
      k_transform<36><<<tgrid, 256, 0, stream>>>(feat, L[0][0], L[0][1], L[0][2], L[0][3], xA, xB, N);
    else
      k_transform<64><<<tgrid, 256, 0, stream>>>(xC, L[l][0], L[l][1], L[l][2], L[l][3], xA, xB, N);
    k_edge<<<ngrid, 256, 0, stream>>>(xA, xB, rowptr, (const int*)pairs,
                                      L[l][4], L[l][5], L[l][6], xC, N);
  }

  k_mean<<<64, 256, 0, stream>>>(xC, part, N);
  k_mlp<<<1, 64, 0, stream>>>(part, 64, Wm1, bm1, Wm2, bm2, Wm3, bm3,
                              (float*)d_out, 1.0 / (double)N);
}

// Round 8
// 724.885 us; speedup vs baseline: 1.4037x; 1.4037x over previous
//
#include <hip/hip_runtime.h>

// ---------------------------------------------------------------------------
// GATv2 x4 + MLP readout.  CSR-by-dst build once per call, then per layer:
//   k_transform: xl = x@Wl+bl, xr = x@Wr+br  (16 nodes/block, float4 acc)
//   k_edge: fused score + online-softmax + aggregate. One wave per NODE,
//     chunk = 16 edges.  Staging: one wave-uniform global_load_lds (size=4)
//     per row into a stride-68 padded tile (R7 lesson: gather-mode lds-DMA
//     with per-lane rows explodes HBM traffic 160->364MB fetch +225MB write;
//     wave-uniform row bases stay L2-friendly).  Score lane=(e,q) dots 16
//     channels of edge e (b128 tile reads); aggregate accumulates in
//     REGISTERS from the score operands (no LDS reads / readlanes); one
//     4-step butterfly over edge-lanes per node at the end.
// CSR build: hist -> scanA -> scanC(+B fused) -> k_scatter (LDS-binned,
//   ~77k spread global atomics) -> k_csr (bucket-local scatter).
// Readout: per-block partial sums (no atomics) + 1-block MLP.
// NOTE: packing requires N <= 65536 (here N = 50000).
// R5 lesson: per-edge global atomics on few lines serialize (~11ns/op).
// ---------------------------------------------------------------------------

__device__ __forceinline__ int rfl(int v) { return __builtin_amdgcn_readfirstlane(v); }

__device__ __forceinline__ void row_to_lds(const float* g, float* l) {
  __builtin_amdgcn_global_load_lds((const __attribute__((address_space(1))) void*)g,
                                   (__attribute__((address_space(3))) void*)l,
                                   4, 0, 0);
}

__global__ void k_hist(const int* __restrict__ dst, int* __restrict__ deg, int E) {
  int e = blockIdx.x * blockDim.x + threadIdx.x;
  if (e < E) atomicAdd(&deg[dst[e]], 1);
}

// ---- scan pass A: per-1024-chunk sums
__global__ void __launch_bounds__(256) k_scanA(const int* __restrict__ deg,
                                               int* __restrict__ bsum, int n) {
  __shared__ int ws[4];
  int tid = threadIdx.x, lane = tid & 63, wv = tid >> 6;
  int base = blockIdx.x * 1024 + tid;
  int s = 0;
  #pragma unroll
  for (int k = 0; k < 4; k++) {
    int i = base + k * 256;
    if (i < n) s += deg[i];
  }
  #pragma unroll
  for (int o = 32; o > 0; o >>= 1) s += __shfl_xor(s, o, 64);
  if (lane == 0) ws[wv] = s;
  __syncthreads();
  if (tid == 0) bsum[blockIdx.x] = ws[0] + ws[1] + ws[2] + ws[3];
}

// ---- scan pass C (with pass B folded in: every block re-scans bsum)
__global__ void __launch_bounds__(256) k_scanC(const int* __restrict__ deg,
                                               const int* __restrict__ bsum,
                                               int* __restrict__ rowptr, int n, int nb) {
  __shared__ int wtot[4];
  __shared__ int sboff;
  int tid = threadIdx.x, lane = tid & 63, wv = tid >> 6;
  if (wv == 0) {
    int v = (lane < nb) ? bsum[lane] : 0;  // nb <= 64
    int x = v;
    #pragma unroll
    for (int o = 1; o < 64; o <<= 1) {
      int t = __shfl_up(x, o, 64);
      if (lane >= o) x += t;
    }
    if (lane == (int)blockIdx.x) sboff = x - v;        // this block's prefix
    if (blockIdx.x == 0 && lane == 63) rowptr[n] = x;  // grand total
  }
  __syncthreads();
  int i0 = blockIdx.x * 1024 + tid * 4;
  int4 v = make_int4(0, 0, 0, 0);
  if (i0 + 3 < n) v = *(const int4*)(deg + i0);
  else {
    if (i0 + 0 < n) v.x = deg[i0 + 0];
    if (i0 + 1 < n) v.y = deg[i0 + 1];
    if (i0 + 2 < n) v.z = deg[i0 + 2];
  }
  int s = v.x + v.y + v.z + v.w;
  int x = s;
  #pragma unroll
  for (int o = 1; o < 64; o <<= 1) {
    int t = __shfl_up(x, o, 64);
    if (lane >= o) x += t;
  }
  if (lane == 63) wtot[wv] = x;
  __syncthreads();
  int wexcl = 0;
  for (int k = 0; k < 4; k++) if (k < wv) wexcl += wtot[k];
  int excl = sboff + wexcl + (x - s);
  int4 o4;
  o4.x = excl; o4.y = o4.x + v.x; o4.z = o4.y + v.y; o4.w = o4.z + v.z;
  if (i0 + 3 < n) *(int4*)(rowptr + i0) = o4;
  else {
    if (i0 + 0 < n) rowptr[i0 + 0] = o4.x;
    if (i0 + 1 < n) rowptr[i0 + 1] = o4.y;
    if (i0 + 2 < n) rowptr[i0 + 2] = o4.z;
  }
}

// ---- pass 1: block-binned scatter into bucket regions (256 dst per bucket)
#define NBK_MAX 256
__global__ void __launch_bounds__(256) k_scatter(
    const int* __restrict__ src, const int* __restrict__ dst,
    const float* __restrict__ ea_in, const int* __restrict__ rowptr,
    int* __restrict__ bcur, uint2* __restrict__ tmp, int E, int nbk) {
  __shared__ int cnt[NBK_MAX];
  __shared__ int cur[NBK_MAX];
  __shared__ int gbase[NBK_MAX];
  __shared__ int sbase[NBK_MAX];
  int tid = threadIdx.x;
  if (tid < nbk) {
    cnt[tid] = 0;
    cur[tid] = 0;
    sbase[tid] = rowptr[tid << 8];
  }
  __syncthreads();
  int base = blockIdx.x * 4096 + tid;
  uint2 rec[16];
  #pragma unroll
  for (int k = 0; k < 16; k++) {
    int e = base + k * 256;
    if (e < E) {
      unsigned d = (unsigned)dst[e];
      rec[k] = make_uint2((d << 16) | (unsigned)src[e],
                          (unsigned)__float_as_int(ea_in[e]));
      atomicAdd(&cnt[d >> 8], 1);
    } else {
      rec[k] = make_uint2(0u, 0u);
    }
  }
  __syncthreads();
  if (tid < nbk) {
    int c = cnt[tid];
    gbase[tid] = (c > 0) ? atomicAdd(&bcur[tid * 16], c) : 0;
  }
  __syncthreads();
  #pragma unroll
  for (int k = 0; k < 16; k++) {
    int e = base + k * 256;
    if (e < E) {
      int b = (int)(rec[k].x >> 24);
      int slot = atomicAdd(&cur[b], 1);
      tmp[sbase[b] + gbase[b] + slot] = rec[k];
    }
  }
}

// ---- pass 2: one block per bucket; LDS cursors; L2-resident final scatter
__global__ void __launch_bounds__(256) k_csr(const int* __restrict__ rowptr,
                                             const uint2* __restrict__ tmp,
                                             int2* __restrict__ pairs, int N) {
  __shared__ int sRP[257];
  __shared__ int cur[256];
  int b = blockIdx.x;
  int n0 = b << 8;
  int tid = threadIdx.x;
  sRP[tid] = rowptr[min(n0 + tid, N)];
  if (tid == 0) sRP[256] = rowptr[min(n0 + 256, N)];
  cur[tid] = 0;
  __syncthreads();
  int lo = sRP[0], hi = sRP[256];
  for (int k = lo + tid; k < hi; k += 256) {
    uint2 rec = tmp[k];
    int local = (int)(rec.x >> 16) - n0;
    int pos = sRP[local] + atomicAdd(&cur[local], 1);
    pairs[pos] = make_int2((int)(rec.x & 0xffffu), (int)rec.y);
  }
}

// xl = x @ Wl + bl ; xr = x @ Wr + br.  16 nodes/block (R6-proven version).
template <int DIN>
__global__ void __launch_bounds__(256) k_transform(
    const float* __restrict__ x, const float* __restrict__ Wl, const float* __restrict__ bl,
    const float* __restrict__ Wr, const float* __restrict__ br,
    float* __restrict__ xl, float* __restrict__ xr, int nNodes) {
  __shared__ __align__(16) float sWl[DIN * 64];
  __shared__ __align__(16) float sWr[DIN * 64];
  __shared__ float sx[16][DIN + 1];
  int tid = threadIdx.x;
  for (int i = tid; i < DIN * 64; i += 256) { sWl[i] = Wl[i]; sWr[i] = Wr[i]; }
  int nb = blockIdx.x * 16;
  for (int i = tid; i < 16 * DIN; i += 256) {
    int ln = i / DIN, c = i % DIN;
    int g = nb + ln;
    sx[ln][c] = (g < nNodes) ? x[(size_t)g * DIN + c] : 0.f;
  }
  __syncthreads();
  int node = tid >> 4;          // 0..15
  int t4 = (tid & 15) * 4;      // col group
  float4 accl = *(const float4*)(bl + t4);
  float4 accr = *(const float4*)(br + t4);
  const float* xrow = sx[node];
  #pragma unroll 4
  for (int k = 0; k < DIN; k++) {
    float xv = xrow[k];
    float4 wl = *(const float4*)(sWl + k * 64 + t4);
    float4 wr = *(const float4*)(sWr + k * 64 + t4);
    accl.x = fmaf(xv, wl.x, accl.x); accl.y = fmaf(xv, wl.y, accl.y);
    accl.z = fmaf(xv, wl.z, accl.z); accl.w = fmaf(xv, wl.w, accl.w);
    accr.x = fmaf(xv, wr.x, accr.x); accr.y = fmaf(xv, wr.y, accr.y);
    accr.z = fmaf(xv, wr.z, accr.z); accr.w = fmaf(xv, wr.w, accr.w);
  }
  int g = nb + node;
  if (g < nNodes) {
    *(float4*)(xl + (size_t)g * 64 + t4) = accl;
    *(float4*)(xr + (size_t)g * 64 + t4) = accr;
  }
}

// Fused score + online softmax + register aggregate. One wave/node, chunk=16.
#define SCGRP(T, W, X, A) \
  u = T.x + fmaf(ea, W.x, X.x); u = fmaxf(u, 0.2f * u); sc = fmaf(A.x, u, sc); \
  u = T.y + fmaf(ea, W.y, X.y); u = fmaxf(u, 0.2f * u); sc = fmaf(A.y, u, sc); \
  u = T.z + fmaf(ea, W.z, X.z); u = fmaxf(u, 0.2f * u); sc = fmaf(A.z, u, sc); \
  u = T.w + fmaf(ea, W.w, X.w); u = fmaxf(u, 0.2f * u); sc = fmaf(A.w, u, sc);
#define AGG(A, T) \
  A.x = fmaf(alpha, T.x, A.x * r); A.y = fmaf(alpha, T.y, A.y * r); \
  A.z = fmaf(alpha, T.z, A.z * r); A.w = fmaf(alpha, T.w, A.w * r);
#define BFLY(A, O) \
  A.x += __shfl_xor(A.x, O, 64); A.y += __shfl_xor(A.y, O, 64); \
  A.z += __shfl_xor(A.z, O, 64); A.w += __shfl_xor(A.w, O, 64);

__global__ void __launch_bounds__(256, 8) k_edge(
    const float* __restrict__ xl, const float* __restrict__ xr,
    const int* __restrict__ rowptr, const int* __restrict__ pairs,  // int2 as int*
    const float* __restrict__ We, const float* __restrict__ att,
    const float* __restrict__ bo, float* __restrict__ xout, int nNodes) {
  __shared__ __align__(16) float tile[4][16 * 68];  // 4.35 KB/wave, stride 68
  __shared__ __align__(16) float sXr[4][64];
  __shared__ __align__(16) float sWe[64];
  __shared__ __align__(16) float sAtt[64];
  __shared__ __align__(16) float sBo[64];
  int tid = threadIdx.x;
  int lane = tid & 63;
  int wv = rfl(tid >> 6);
  int n = rfl(blockIdx.x * 4 + wv);
  if (tid < 64) { sWe[tid] = We[tid]; sAtt[tid] = att[tid]; sBo[tid] = bo[tid]; }
  bool active = (n < nNodes);
  if (active) sXr[wv][lane] = xr[(size_t)n * 64 + lane];
  __syncthreads();
  if (!active) return;

  float* tw = tile[wv];
  int s0 = rfl(rowptr[n]);
  int s1 = rfl(rowptr[n + 1]);
  int e = lane & 15, q = lane >> 4;
  const float* trow = tw + e * 68 + q * 16;  // kernel-invariant per-lane addr
  const float* xq = sXr[wv] + q * 16;
  const float* wq = sWe + q * 16;
  const float* aq = sAtt + q * 16;

  float m = -3.0e38f, d = 0.f;
  float4 A0 = {0.f, 0.f, 0.f, 0.f}, A1 = A0, A2 = A0, A3 = A0;

  for (int kb = s0; kb < s1; kb += 16) {
    int cnt = rfl(min(16, s1 - kb));
    int raw = 0;
    if (lane < 2 * cnt) raw = pairs[2 * kb + lane];
    float ea = __int_as_float(__shfl(raw, 2 * e + 1, 64));

    // ---- stage rows: one WAVE-UNIFORM lds-DMA per row (R6-proven, L2-kind)
    for (int j = 0; j < cnt; ++j) {
      int s = __builtin_amdgcn_readlane(raw, 2 * j);
      row_to_lds(xl + (size_t)(unsigned)s * 64 + lane, tw + j * 68);
    }
    __builtin_amdgcn_s_waitcnt(0);

    // ---- score: lane (e,q) dots channels [16q,16q+16) of edge e
    // (stale tile rows for e >= cnt are finite garbage; alpha=0 masks them)
    float4 t0 = *(const float4*)(trow + 0);
    float4 t1 = *(const float4*)(trow + 4);
    float4 t2 = *(const float4*)(trow + 8);
    float4 t3 = *(const float4*)(trow + 12);
    float4 x0 = *(const float4*)(xq + 0),  x1 = *(const float4*)(xq + 4);
    float4 x2 = *(const float4*)(xq + 8),  x3 = *(const float4*)(xq + 12);
    float4 w0 = *(const float4*)(wq + 0),  w1 = *(const float4*)(wq + 4);
    float4 w2 = *(const float4*)(wq + 8),  w3 = *(const float4*)(wq + 12);
    float4 a0 = *(const float4*)(aq + 0),  a1 = *(const float4*)(aq + 4);
    float4 a2 = *(const float4*)(aq + 8),  a3 = *(const float4*)(aq + 12);
    float sc = 0.f, u;
    SCGRP(t0, w0, x0, a0)
    SCGRP(t1, w1, x1, a1)
    SCGRP(t2, w2, x2, a2)
    SCGRP(t3, w3, x3, a3)
    sc += __shfl_xor(sc, 16, 64);   // combine the 4 channel quarters
    sc += __shfl_xor(sc, 32, 64);
    sc = (e < cnt) ? sc : -3.0e38f; // padded edges -> alpha = 0

    // ---- online softmax over 16 edges (quarter-duplicated lanes)
    float mc = sc;
    #pragma unroll
    for (int o = 1; o <= 8; o <<= 1) mc = fmaxf(mc, __shfl_xor(mc, o, 64));
    float newm = fmaxf(m, mc);
    float r = expf(m - newm);       // 0 on first chunk, 1 if max unchanged
    float alpha = expf(sc - newm);
    float ds = alpha;
    #pragma unroll
    for (int o = 1; o <= 8; o <<= 1) ds += __shfl_xor(ds, o, 64);
    d = d * r + ds;
    m = newm;

    // ---- aggregate in registers: acc16 += alpha_e * tv  (no LDS reads)
    AGG(A0, t0) AGG(A1, t1) AGG(A2, t2) AGG(A3, t3)
  }

  // sum over the 16 edge-lanes within each q-group (once per node)
  BFLY(A0, 1) BFLY(A1, 1) BFLY(A2, 1) BFLY(A3, 1)
  BFLY(A0, 2) BFLY(A1, 2) BFLY(A2, 2) BFLY(A3, 2)
  BFLY(A0, 4) BFLY(A1, 4) BFLY(A2, 4) BFLY(A3, 4)
  BFLY(A0, 8) BFLY(A1, 8) BFLY(A2, 8) BFLY(A3, 8)

  float inv = 1.f / (d + 1e-16f);
  if (e == 0) {
    float* op = xout + (size_t)n * 64 + q * 16;
    float4 b0 = *(const float4*)(sBo + q * 16 + 0);
    float4 b1 = *(const float4*)(sBo + q * 16 + 4);
    float4 b2 = *(const float4*)(sBo + q * 16 + 8);
    float4 b3 = *(const float4*)(sBo + q * 16 + 12);
    float4 o0, o1, o2, o3;
    o0.x = fmaxf(fmaf(A0.x, inv, b0.x), 0.f); o0.y = fmaxf(fmaf(A0.y, inv, b0.y), 0.f);
    o0.z = fmaxf(fmaf(A0.z, inv, b0.z), 0.f); o0.w = fmaxf(fmaf(A0.w, inv, b0.w), 0.f);
    o1.x = fmaxf(fmaf(A1.x, inv, b1.x), 0.f); o1.y = fmaxf(fmaf(A1.y, inv, b1.y), 0.f);
    o1.z = fmaxf(fmaf(A1.z, inv, b1.z), 0.f); o1.w = fmaxf(fmaf(A1.w, inv, b1.w), 0.f);
    o2.x = fmaxf(fmaf(A2.x, inv, b2.x), 0.f); o2.y = fmaxf(fmaf(A2.y, inv, b2.y), 0.f);
    o2.z = fmaxf(fmaf(A2.z, inv, b2.z), 0.f); o2.w = fmaxf(fmaf(A2.w, inv, b2.w), 0.f);
    o3.x = fmaxf(fmaf(A3.x, inv, b3.x), 0.f); o3.y = fmaxf(fmaf(A3.y, inv, b3.y), 0.f);
    o3.z = fmaxf(fmaf(A3.z, inv, b3.z), 0.f); o3.w = fmaxf(fmaf(A3.w, inv, b3.w), 0.f);
    *(float4*)(op + 0)  = o0;
    *(float4*)(op + 4)  = o1;
    *(float4*)(op + 8)  = o2;
    *(float4*)(op + 12) = o3;
  }
}

// per-block partial sums (no atomics); k_mlp reduces the 64 partials
__global__ void k_mean(const float* __restrict__ x, float* __restrict__ part, int nNodes) {
  __shared__ float sacc[256];
  int lane = threadIdx.x & 63;
  int gw = blockIdx.x * 4 + (threadIdx.x >> 6);
  int stride = gridDim.x * 4;
  float acc = 0.f;
  for (int n = gw; n < nNodes; n += stride) acc += x[(size_t)n * 64 + lane];
  sacc[threadIdx.x] = acc;
  __syncthreads();
  if (threadIdx.x < 64)
    part[blockIdx.x * 64 + threadIdx.x] =
        sacc[threadIdx.x] + sacc[threadIdx.x + 64] + sacc[threadIdx.x + 128] + sacc[threadIdx.x + 192];
}

__global__ void k_mlp(const float* __restrict__ part, int nparts,
                      const float* __restrict__ Wm1, const float* __restrict__ bm1,
                      const float* __restrict__ Wm2, const float* __restrict__ bm2,
                      const float* __restrict__ Wm3, const float* __restrict__ bm3,
                      float* __restrict__ out, double invN) {
  __shared__ float xm[64];
  __shared__ float h1[32];
  __shared__ float h2[16];
  int t = threadIdx.x;
  double s = 0.0;
  for (int b = 0; b < nparts; b++) s += (double)part[b * 64 + t];
  xm[t] = (float)(s * invN);
  __syncthreads();
  if (t < 32) {
    float a = bm1[t];
    for (int c = 0; c < 64; c++) a = fmaf(xm[c], Wm1[c * 32 + t], a);
    h1[t] = fmaxf(a, 0.f);
  }
  __syncthreads();
  if (t < 16) {
    float a = bm2[t];
    for (int c = 0; c < 32; c++) a = fmaf(h1[c], Wm2[c * 16 + t], a);
    h2[t] = fmaxf(a, 0.f);
  }
  __syncthreads();
  if (t == 0) {
    float a = bm3[0];
    for (int c = 0; c < 16; c++) a = fmaf(h2[c], Wm3[c], a);
    out[0] = a;
  }
}

extern "C" void kernel_launch(void* const* d_in, const int* in_sizes, int n_in,
                              void* d_out, int out_size, void* d_ws, size_t ws_size,
                              hipStream_t stream) {
  (void)n_in; (void)out_size; (void)ws_size;
  const int N = in_sizes[0] / 36;   // 50000
  const int E = in_sizes[1];        // 1600000

  const float* feat = (const float*)d_in[0];
  const float* eat  = (const float*)d_in[1];
  const int*   eidx = (const int*)d_in[2];
  const int* src = eidx;
  const int* dst = eidx + E;

  const float* L[4][7];  // Wl, bl, Wr, br, We, att, bo
  for (int l = 0; l < 4; l++)
    for (int j = 0; j < 7; j++) L[l][j] = (const float*)d_in[3 + l * 7 + j];
  const float* Wm1 = (const float*)d_in[31];
  const float* bm1 = (const float*)d_in[32];
  const float* Wm2 = (const float*)d_in[33];
  const float* bm2 = (const float*)d_in[34];
  const float* Wm3 = (const float*)d_in[35];
  const float* bm3 = (const float*)d_in[36];

  const int NBK = (N + 255) >> 8;  // buckets of 256 dst nodes (196)

  // workspace layout (512B aligned)
  char* ws = (char*)d_ws;
  size_t off = 0;
  auto alloc = [&](size_t bytes) {
    off = (off + 511) & ~(size_t)511;
    void* p = ws + off;
    off += bytes;
    return p;
  };
  int*    deg     = (int*)alloc((size_t)N * 4);
  int*    bcur    = (int*)alloc((size_t)NBK * 16 * 4);  // 1 counter per 64B line
  size_t zero_bytes = off;  // deg + bcur
  int*    rowptr  = (int*)alloc((size_t)(N + 1) * 4);
  int*    bsum    = (int*)alloc(64 * 4);
  float*  part    = (float*)alloc(64 * 64 * 4);
  int2*   pairs   = (int2*)alloc((size_t)E * 8);
  float*  xA      = (float*)alloc((size_t)N * 64 * 4);  // xl
  float*  xB      = (float*)alloc((size_t)N * 64 * 4);  // xr
  float*  xC      = (float*)alloc((size_t)N * 64 * 4);  // layer out / next in
  uint2*  tmp     = (uint2*)xC;  // aliases xC: dead until k_edge layer 1 writes it

  hipMemsetAsync(d_ws, 0, zero_bytes, stream);

  int egrid = (E + 255) / 256;
  int sgrid = (E + 4095) / 4096; // k_scatter: 4096 edges per 256-thr block
  int tgrid = (N + 15) / 16;     // k_transform: 16 nodes per 256-thr block
  int ngrid = (N + 3) / 4;       // k_edge: 4 nodes (waves) per 256-thr block
  int nb = (N + 1023) / 1024;    // scan blocks (49 <= 64)

  k_hist<<<egrid, 256, 0, stream>>>(dst, deg, E);
  k_scanA<<<nb, 256, 0, stream>>>(deg, bsum, N);
  k_scanC<<<nb, 256, 0, stream>>>(deg, bsum, rowptr, N, nb);
  k_scatter<<<sgrid, 256, 0, stream>>>(src, dst, eat, rowptr, bcur, tmp, E, NBK);
  k_csr<<<NBK, 256, 0, stream>>>(rowptr, tmp, pairs, N);

  for (int l = 0; l < 4; l++) {
    if (l == 0)
      k_transform<36><<<tgrid, 256, 0, stream>>>(feat, L[0][0], L[0][1], L[0][2], L[0][3], xA, xB, N);
    else
      k_transform<64><<<tgrid, 256, 0, stream>>>(xC, L[l][0], L[l][1], L[l][2], L[l][3], xA, xB, N);
    k_edge<<<ngrid, 256, 0, stream>>>(xA, xB, rowptr, (const int*)pairs,
                                      L[l][4], L[l][5], L[l][6], xC, N);
  }

  k_mean<<<64, 256, 0, stream>>>(xC, part, N);
  k_mlp<<<1, 64, 0, stream>>>(part, 64, Wm1, bm1, Wm2, bm2, Wm3, bm3,
                              (float*)d_out, 1.0 / (double)N);
}